// Round 3
// baseline (4650.261 us; speedup 1.0000x reference)
//
#include <hip/hip_runtime.h>
#include <hip/hip_bf16.h>

typedef __hip_bfloat16 bf16;
typedef short v8s __attribute__((ext_vector_type(8)));
typedef float v4f __attribute__((ext_vector_type(4)));

#define BATCH 256
#define SEQ 64
#define INPUT 512
#define HIDDEN 1024
#define CLASSES 1000

// ============================================================================
// Fragment-linear layouts (bf16), unchanged from round 2:
//   A-chunk (16 m x 32 k): chunk[lane*8+j] = A[m16*16 + (lane&15)][k32*32 + (lane>>4)*8 + j]
//   B-chunk (16 n x 32 k): chunk[lane*8+j] = W[k32*32 + (lane>>4)*8 + j][ncol]
// Xfrag:  [t][m16(16)][k32(16)][512]
// h-frag: [t][m16(16)][k32(32)][512]   (deep-buffered: one full h per timestep)
// Bf:     [n16(256: g*64+h16)][k32(nT)][512]
// Wof:    [n16(64)][k32(32)][512]
// ============================================================================

__global__ __launch_bounds__(256) void conv_x(const float* __restrict__ x,
                                              bf16* __restrict__ Xf) {
    int gid = blockIdx.x * 256 + threadIdx.x;
    int lane = gid & 63;
    int k32 = (gid >> 6) & 15;
    int m16 = (gid >> 10) & 15;
    int tt  = gid >> 14;
    int row = lane & 15, quad = lane >> 4;
    int b_ = m16 * 16 + row;
    int k  = k32 * 32 + quad * 8;
    const float* src = x + ((size_t)(b_ * SEQ + tt) * INPUT + k);
    float4 v0 = *(const float4*)src;
    float4 v1 = *(const float4*)(src + 4);
    bf16 o[8] = {__float2bfloat16(v0.x), __float2bfloat16(v0.y),
                 __float2bfloat16(v0.z), __float2bfloat16(v0.w),
                 __float2bfloat16(v1.x), __float2bfloat16(v1.y),
                 __float2bfloat16(v1.z), __float2bfloat16(v1.w)};
    bf16* dst = Xf + (size_t)(tt * 256 + m16 * 16 + k32) * 512 + lane * 8;
    *(v8s*)dst = *(v8s*)o;
}

__global__ __launch_bounds__(256) void build_bf(const float* __restrict__ W,
                                                const float* __restrict__ U,
                                                int K0, int nT,
                                                bf16* __restrict__ dst) {
    __shared__ float tile[64][17];
    const int g = blockIdx.z, h16 = blockIdx.y, kt = blockIdx.x;
    const int k0 = kt * 64;
    const int cb = g * 1024 + h16 * 16;
    const int tid = threadIdx.x;
#pragma unroll
    for (int i = 0; i < 4; i++) {
        int idx = tid + i * 256;
        int kl = idx >> 4, c = idx & 15;
        int k = k0 + kl;
        float v = (k < K0) ? W[(size_t)k * 4096 + cb + c]
                           : U[(size_t)(k - K0) * 4096 + cb + c];
        tile[kl][c] = v;
    }
    __syncthreads();
    if (tid < 128) {
        int k32l = tid >> 6, l = tid & 63;
        int col = l & 15, quad = l >> 4;
        bf16 o[8];
#pragma unroll
        for (int j = 0; j < 8; j++)
            o[j] = __float2bfloat16(tile[k32l * 32 + quad * 8 + j][col]);
        int n16 = g * 64 + h16;
        int k32 = kt * 2 + k32l;
        *(v8s*)(dst + (size_t)(n16 * nT + k32) * 512 + l * 8) = *(v8s*)o;
    }
}

__global__ __launch_bounds__(256) void build_wof(const float* __restrict__ Wo,
                                                 bf16* __restrict__ dst) {
    __shared__ float tile[64][17];
    const int h16 = blockIdx.y, kt = blockIdx.x;
    const int k0 = kt * 64, nb = h16 * 16;
    const int tid = threadIdx.x;
#pragma unroll
    for (int i = 0; i < 4; i++) {
        int idx = tid + i * 256;
        int kl = idx >> 4, c = idx & 15;
        int k = k0 + kl;
        float v = (nb + c < CLASSES) ? Wo[(size_t)k * CLASSES + nb + c] : 0.f;
        tile[kl][c] = v;
    }
    __syncthreads();
    if (tid < 128) {
        int k32l = tid >> 6, l = tid & 63;
        int col = l & 15, quad = l >> 4;
        bf16 o[8];
#pragma unroll
        for (int j = 0; j < 8; j++)
            o[j] = __float2bfloat16(tile[k32l * 32 + quad * 8 + j][col]);
        int k32 = kt * 2 + k32l;
        *(v8s*)(dst + (size_t)(h16 * 32 + k32) * 512 + l * 8) = *(v8s*)o;
    }
}

// ---------------------------------------------------------------------------
// Persistent LSTM kernel. 512 blocks x 128 threads (2 waves), all co-resident:
//   worst case (>=257 VGPR) 1 wave/SIMD -> 4 waves/CU -> 2 blocks/CU -> 512 OK.
//   LDS 34 KB/block -> 2/CU OK.
// blocks 0..255: layer 1, blocks 256..511: layer 2. idx = b&255: hblk=idx&63,
// mt=idx>>6. b%8 == hblk%8 for both layers -> per-XCD weight slice ~3.5 MB.
// Each block: 64 batch x 64 n (4 gates x 16 h), waves split K in half, 4x4
// fragment tile (16 MFMA / 8KB fragments), LDS reduction, fused cell epilogue.
// Cross-t sync: done1[t]/done2[t] device-scope counters (256 producers each).
// All h(t) deep-buffered -> no anti-deps, no stale-cache risk.
// ---------------------------------------------------------------------------
__device__ inline void spinwait(const int* p, int target) {
    while (__hip_atomic_load(p, __ATOMIC_ACQUIRE, __HIP_MEMORY_SCOPE_AGENT) < target)
        __builtin_amdgcn_s_sleep(8);
}

__global__ __launch_bounds__(128, 1) void lstm_persist(
    const bf16* __restrict__ Xf,
    const bf16* __restrict__ Bf1, const bf16* __restrict__ Bf2,
    const float* __restrict__ bias1, const float* __restrict__ bias2,
    bf16* __restrict__ h1all, bf16* __restrict__ h2all,
    const bf16* __restrict__ hz,
    float* __restrict__ c1, float* __restrict__ c2,
    int* __restrict__ flags1, int* __restrict__ flags2)
{
    const int b = blockIdx.x;
    const int layer = b >> 8;
    const int idx = b & 255;
    const int hblk = idx & 63;
    const int mt = idx >> 6;

    const int nT = layer ? 64 : 48;      // total k-chunks
    const int nA = layer ? 32 : 16;      // chunks from A0
    const int half = nT >> 1;
    const bf16* __restrict__ Bf = layer ? Bf2 : Bf1;
    const float* __restrict__ bias = layer ? bias2 : bias1;
    float* __restrict__ cptr = layer ? c2 : c1;
    int* myflags = layer ? flags2 : flags1;
    bf16* hall = layer ? h2all : h1all;
    const size_t HB = (size_t)BATCH * HIDDEN;

    const int tid = threadIdx.x;
    const int kk = tid >> 6;             // K-half owned by this wave
    const int lane = tid & 63;
    const int col = lane & 15, quad = lane >> 4;

    __shared__ float red[16 * 64 * 4];   // 16 KB partial-sum exchange
    __shared__ float Zs[64][68];         // 17.4 KB z staging

    const bf16* Bb[4];
#pragma unroll
    for (int g = 0; g < 4; g++)
        Bb[g] = Bf + (size_t)((g * 64 + hblk) * nT) * 512 + lane * 8;

    const float bv[4] = {bias[0 * 1024 + hblk * 16 + col],
                         bias[1 * 1024 + hblk * 16 + col],
                         bias[2 * 1024 + hblk * 16 + col],
                         bias[3 * 1024 + hblk * 16 + col]};

    for (int t = 0; t < SEQ; t++) {
        // ---- wait for producers ----
        if (tid == 0) {
            if (layer == 0) {
                if (t > 0) spinwait(flags1 + (t - 1) * 64, 256);
            } else {
                spinwait(flags1 + t * 64, 256);
                if (t > 0) spinwait(flags2 + (t - 1) * 64, 256);
            }
        }
        __syncthreads();

        const bf16 *A0base, *A1base;
        if (layer == 0) {
            A0base = Xf + (size_t)t * (BATCH * INPUT);
            A1base = t ? (h1all + (size_t)(t - 1) * HB) : hz;
        } else {
            A0base = h1all + (size_t)t * HB;
            A1base = t ? (h2all + (size_t)(t - 1) * HB) : hz;
        }
        const bf16 *ax[4], *ah[4];
#pragma unroll
        for (int i = 0; i < 4; i++) {
            int m16 = mt * 4 + i;
            ax[i] = A0base + (size_t)(m16 * nA) * 512 + lane * 8;
            ah[i] = A1base + (size_t)(m16 * 32) * 512 + lane * 8;
        }

        v4f acc[4][4] = {};
        v8s ra[4][4], rb[4][4];
        const int kbase = kk * half;

#define ISSUE(KCH, SLOT) do {                                                   \
    const int k_ = (KCH);                                                       \
    _Pragma("unroll")                                                           \
    for (int i_ = 0; i_ < 4; i_++) {                                            \
        const bf16* p_ = (k_ < nA) ? (ax[i_] + (size_t)k_ * 512)                \
                                   : (ah[i_] + (size_t)(k_ - nA) * 512);        \
        ra[SLOT][i_] = *(const v8s*)p_;                                         \
    }                                                                           \
    _Pragma("unroll")                                                           \
    for (int g_ = 0; g_ < 4; g_++)                                              \
        rb[SLOT][g_] = *(const v8s*)(Bb[g_] + (size_t)k_ * 512);                \
} while (0)

        ISSUE(kbase + 0, 0); ISSUE(kbase + 1, 1);
        ISSUE(kbase + 2, 2); ISSUE(kbase + 3, 3);

        for (int j0 = 0; j0 < half; j0 += 4) {
#pragma unroll
            for (int s = 0; s < 4; s++) {
#pragma unroll
                for (int mi = 0; mi < 4; mi++)
#pragma unroll
                    for (int g = 0; g < 4; g++)
                        acc[mi][g] = __builtin_amdgcn_mfma_f32_16x16x32_bf16(
                            ra[s][mi], rb[s][g], acc[mi][g], 0, 0, 0);
                const int nj = j0 + s + 4;
                if (nj < half) ISSUE(kbase + nj, s);
            }
        }
#undef ISSUE

        // ---- K-split reduction: wave1 -> LDS, wave0 adds ----
        if (kk == 1) {
#pragma unroll
            for (int mi = 0; mi < 4; mi++)
#pragma unroll
                for (int g = 0; g < 4; g++)
                    *(v4f*)&red[(((mi * 4 + g) * 64) + lane) * 4] = acc[mi][g];
        }
        __syncthreads();
        if (kk == 0) {
#pragma unroll
            for (int mi = 0; mi < 4; mi++)
#pragma unroll
                for (int g = 0; g < 4; g++) {
                    v4f o = *(v4f*)&red[(((mi * 4 + g) * 64) + lane) * 4];
                    v4f z = acc[mi][g] + o;
#pragma unroll
                    for (int r = 0; r < 4; r++)
                        Zs[mi * 16 + quad * 4 + r][col * 4 + g] = z[r] + bv[g];
                }
        }
        __syncthreads();

        // ---- fused LSTM cell: 64 m x 16 h, 8 cells/thread ----
        {
            const int m = tid >> 1, ch = tid & 1;
            const int mg = mt * 64 + m;
            const int hg = hblk * 16 + ch * 8;
            float* cp = cptr + (size_t)mg * HIDDEN + hg;
            float4 cv0 = *(float4*)cp;
            float4 cv1 = *(float4*)(cp + 4);
            float cold[8] = {cv0.x, cv0.y, cv0.z, cv0.w, cv1.x, cv1.y, cv1.z, cv1.w};
            float cnew[8];
            bf16 hv[8];
#pragma unroll
            for (int hh = 0; hh < 8; hh++) {
                const int zc = (ch * 8 + hh) * 4;
                float zi = Zs[m][zc], zf = Zs[m][zc + 1];
                float zg = Zs[m][zc + 2], zo = Zs[m][zc + 3];
                float ig = 1.f / (1.f + __expf(-zi));
                float fg = 1.f / (1.f + __expf(-zf));
                float e2g = __expf(2.f * zg);
                float gg = (e2g - 1.f) / (e2g + 1.f);
                float og = 1.f / (1.f + __expf(-zo));
                float cn = fg * cold[hh] + ig * gg;
                float e2c = __expf(2.f * cn);
                float th = (e2c - 1.f) / (e2c + 1.f);
                cnew[hh] = cn;
                hv[hh] = __float2bfloat16(og * th);
            }
            *(float4*)cp = make_float4(cnew[0], cnew[1], cnew[2], cnew[3]);
            *(float4*)(cp + 4) = make_float4(cnew[4], cnew[5], cnew[6], cnew[7]);
            bf16* hout = hall + (size_t)t * HB;
            const size_t hoff = (size_t)(((mg >> 4) * 32 + (hg >> 5)) * 64
                                         + ((hg >> 3) & 3) * 16 + (mg & 15)) * 8;
            *(v8s*)(hout + hoff) = *(v8s*)hv;
        }
        __syncthreads();   // drains vmcnt: all block stores at least in L2

        if (tid == 0) {
            __threadfence();   // agent-scope: L2 writeback -> visible cross-XCD
            __hip_atomic_fetch_add(myflags + t * 64, 1,
                                   __ATOMIC_RELEASE, __HIP_MEMORY_SCOPE_AGENT);
        }
    }
}

// ---------------- projection: out = h2(63) @ Wo + bo ----------------
__global__ __launch_bounds__(256, 2) void proj_kernel(
    const bf16* __restrict__ H,
    const bf16* __restrict__ Wof,
    const float* __restrict__ bo,
    float* __restrict__ Out)
{
    const int mblk = blockIdx.x, nblk = blockIdx.y;
    const int tid = threadIdx.x;
    const int lane = tid & 63;
    const int wave = tid >> 6;
    const int mw = wave >> 1, nw = wave & 1;
    const int col = lane & 15, quad = lane >> 4;

    const int m16 = mblk * 4 + mw * 2;
    const bf16* ah0 = H + (size_t)(m16 * 32) * 512 + lane * 8;
    const bf16* ah1 = H + (size_t)((m16 + 1) * 32) * 512 + lane * 8;
    const int n16a = nblk * 4 + nw * 2, n16b = n16a + 1;
    const bf16* bb0 = Wof + (size_t)(n16a * 32) * 512 + lane * 8;
    const bf16* bb1 = Wof + (size_t)(n16b * 32) * 512 + lane * 8;

    v4f acc00{}, acc01{}, acc10{}, acc11{};
    v8s ra0[8], ra1[8], rb0[8], rb1[8];

#define ISSUE(KK, SLOT) do {                          \
    const int kk_ = (KK);                             \
    ra0[SLOT] = *(const v8s*)(ah0 + kk_ * 512);       \
    ra1[SLOT] = *(const v8s*)(ah1 + kk_ * 512);       \
    rb0[SLOT] = *(const v8s*)(bb0 + kk_ * 512);       \
    rb1[SLOT] = *(const v8s*)(bb1 + kk_ * 512);       \
} while (0)

#pragma unroll
    for (int u = 0; u < 8; u++) ISSUE(u, u);

    for (int base = 0; base < 32; base += 8) {
#pragma unroll
        for (int u = 0; u < 8; u++) {
            acc00 = __builtin_amdgcn_mfma_f32_16x16x32_bf16(ra0[u], rb0[u], acc00, 0, 0, 0);
            acc01 = __builtin_amdgcn_mfma_f32_16x16x32_bf16(ra0[u], rb1[u], acc01, 0, 0, 0);
            acc10 = __builtin_amdgcn_mfma_f32_16x16x32_bf16(ra1[u], rb0[u], acc10, 0, 0, 0);
            acc11 = __builtin_amdgcn_mfma_f32_16x16x32_bf16(ra1[u], rb1[u], acc11, 0, 0, 0);
            const int k2 = base + u + 8;
            if (k2 < 32) ISSUE(k2, u);
        }
    }
#undef ISSUE

    const int n0 = n16a * 16 + col, n1 = n16b * 16 + col;
    const float bo0 = (n0 < CLASSES) ? bo[n0] : 0.f;
    const float bo1 = (n1 < CLASSES) ? bo[n1] : 0.f;
#pragma unroll
    for (int i = 0; i < 2; i++) {
        const int row = mblk * 64 + mw * 32 + i * 16 + quad * 4;
        v4f a0 = i ? acc10 : acc00;
        v4f a1 = i ? acc11 : acc01;
#pragma unroll
        for (int r = 0; r < 4; r++) {
            if (n0 < CLASSES) Out[(size_t)(row + r) * CLASSES + n0] = a0[r] + bo0;
            if (n1 < CLASSES) Out[(size_t)(row + r) * CLASSES + n1] = a1[r] + bo1;
        }
    }
}

// ---------------- launcher ----------------
extern "C" void kernel_launch(void* const* d_in, const int* in_sizes, int n_in,
                              void* d_out, int out_size, void* d_ws, size_t ws_size,
                              hipStream_t stream) {
    const float* x  = (const float*)d_in[0];
    const float* W1 = (const float*)d_in[1];
    const float* U1 = (const float*)d_in[2];
    const float* b1 = (const float*)d_in[3];
    const float* W2 = (const float*)d_in[4];
    const float* U2 = (const float*)d_in[5];
    const float* b2 = (const float*)d_in[6];
    const float* Wo = (const float*)d_in[7];
    const float* bo = (const float*)d_in[8];
    float* out = (float*)d_out;

    char* ws = (char*)d_ws;
    size_t off = 0;
    auto alloc = [&](size_t bytes) -> void* {
        void* p = ws + off;
        off += (bytes + 255) & ~(size_t)255;
        return p;
    };
    bf16* Xf    = (bf16*)alloc((size_t)SEQ * BATCH * INPUT * 2);   // 16.8 MB
    bf16* Bf1   = (bf16*)alloc((size_t)256 * 48 * 512 * 2);        // 12.6 MB
    bf16* Bf2   = (bf16*)alloc((size_t)256 * 64 * 512 * 2);        // 16.8 MB
    bf16* Wof   = (bf16*)alloc((size_t)64 * 32 * 512 * 2);         // 2 MB
    bf16* h1all = (bf16*)alloc((size_t)SEQ * BATCH * HIDDEN * 2);  // 33.6 MB
    bf16* h2all = (bf16*)alloc((size_t)SEQ * BATCH * HIDDEN * 2);  // 33.6 MB
    bf16* hz    = (bf16*)alloc((size_t)BATCH * HIDDEN * 2);
    float* c1   = (float*)alloc((size_t)BATCH * HIDDEN * 4);
    float* c2   = (float*)alloc((size_t)BATCH * HIDDEN * 4);
    int* flags1 = (int*)alloc(64 * 64 * 4);                        // 256B-spaced counters
    int* flags2 = (int*)alloc(64 * 64 * 4);

    hipMemsetAsync(hz, 0, (size_t)BATCH * HIDDEN * 2, stream);
    hipMemsetAsync(c1, 0, (size_t)BATCH * HIDDEN * 4, stream);
    hipMemsetAsync(c2, 0, (size_t)BATCH * HIDDEN * 4, stream);
    hipMemsetAsync(flags1, 0, 64 * 64 * 4, stream);
    hipMemsetAsync(flags2, 0, 64 * 64 * 4, stream);

    conv_x<<<4096, 256, 0, stream>>>(x, Xf);
    build_bf<<<dim3(24, 64, 4), 256, 0, stream>>>(W1, U1, 512, 48, Bf1);
    build_bf<<<dim3(32, 64, 4), 256, 0, stream>>>(W2, U2, 1024, 64, Bf2);
    build_wof<<<dim3(16, 64), 256, 0, stream>>>(Wo, Wof);

    lstm_persist<<<512, 128, 0, stream>>>(Xf, Bf1, Bf2, b1, b2,
                                          h1all, h2all, hz, c1, c2,
                                          flags1, flags2);

    proj_kernel<<<dim3(4, 16), 256, 0, stream>>>(
        h2all + (size_t)(SEQ - 1) * BATCH * HIDDEN, Wof, bo, out);
}

// Round 4
// 2028.791 us; speedup vs baseline: 2.2921x; 2.2921x over previous
//
#include <hip/hip_runtime.h>
#include <hip/hip_bf16.h>

typedef __hip_bfloat16 bf16;
typedef short v8s __attribute__((ext_vector_type(8)));
typedef float v4f __attribute__((ext_vector_type(4)));

#define BATCH 256
#define SEQ 64
#define INPUT 512
#define HIDDEN 1024
#define CLASSES 1000

// ============================================================================
// Fragment-linear layouts (bf16):
//   A-chunk (16 m x 32 k): chunk[lane*8+j] = A[m16*16 + (lane&15)][k32*32 + (lane>>4)*8 + j]
//   B-chunk (16 n x 32 k): chunk[lane*8+j] = W[k32*32 + (lane>>4)*8 + j][ncol]
// Xfrag:  [t][m16(16)][k32(16)][512]
// h-frag: [t][m16(16)][k32(32)][512]   (deep-buffered, write-once per address)
// Bf:     [n16(256: g*64+h16)][k32(nT)][512]
// Wof:    [n16(64)][k32(32)][512]
// ============================================================================

__global__ __launch_bounds__(256) void conv_x(const float* __restrict__ x,
                                              bf16* __restrict__ Xf) {
    int gid = blockIdx.x * 256 + threadIdx.x;
    int lane = gid & 63;
    int k32 = (gid >> 6) & 15;
    int m16 = (gid >> 10) & 15;
    int tt  = gid >> 14;
    int row = lane & 15, quad = lane >> 4;
    int b_ = m16 * 16 + row;
    int k  = k32 * 32 + quad * 8;
    const float* src = x + ((size_t)(b_ * SEQ + tt) * INPUT + k);
    float4 v0 = *(const float4*)src;
    float4 v1 = *(const float4*)(src + 4);
    bf16 o[8] = {__float2bfloat16(v0.x), __float2bfloat16(v0.y),
                 __float2bfloat16(v0.z), __float2bfloat16(v0.w),
                 __float2bfloat16(v1.x), __float2bfloat16(v1.y),
                 __float2bfloat16(v1.z), __float2bfloat16(v1.w)};
    bf16* dst = Xf + (size_t)(tt * 256 + m16 * 16 + k32) * 512 + lane * 8;
    *(v8s*)dst = *(v8s*)o;
}

__global__ __launch_bounds__(256) void build_bf(const float* __restrict__ W,
                                                const float* __restrict__ U,
                                                int K0, int nT,
                                                bf16* __restrict__ dst) {
    __shared__ float tile[64][17];
    const int g = blockIdx.z, h16 = blockIdx.y, kt = blockIdx.x;
    const int k0 = kt * 64;
    const int cb = g * 1024 + h16 * 16;
    const int tid = threadIdx.x;
#pragma unroll
    for (int i = 0; i < 4; i++) {
        int idx = tid + i * 256;
        int kl = idx >> 4, c = idx & 15;
        int k = k0 + kl;
        float v = (k < K0) ? W[(size_t)k * 4096 + cb + c]
                           : U[(size_t)(k - K0) * 4096 + cb + c];
        tile[kl][c] = v;
    }
    __syncthreads();
    if (tid < 128) {
        int k32l = tid >> 6, l = tid & 63;
        int col = l & 15, quad = l >> 4;
        bf16 o[8];
#pragma unroll
        for (int j = 0; j < 8; j++)
            o[j] = __float2bfloat16(tile[k32l * 32 + quad * 8 + j][col]);
        int n16 = g * 64 + h16;
        int k32 = kt * 2 + k32l;
        *(v8s*)(dst + (size_t)(n16 * nT + k32) * 512 + l * 8) = *(v8s*)o;
    }
}

__global__ __launch_bounds__(256) void build_wof(const float* __restrict__ Wo,
                                                 bf16* __restrict__ dst) {
    __shared__ float tile[64][17];
    const int h16 = blockIdx.y, kt = blockIdx.x;
    const int k0 = kt * 64, nb = h16 * 16;
    const int tid = threadIdx.x;
#pragma unroll
    for (int i = 0; i < 4; i++) {
        int idx = tid + i * 256;
        int kl = idx >> 4, c = idx & 15;
        int k = k0 + kl;
        float v = (nb + c < CLASSES) ? Wo[(size_t)k * CLASSES + nb + c] : 0.f;
        tile[kl][c] = v;
    }
    __syncthreads();
    if (tid < 128) {
        int k32l = tid >> 6, l = tid & 63;
        int col = l & 15, quad = l >> 4;
        bf16 o[8];
#pragma unroll
        for (int j = 0; j < 8; j++)
            o[j] = __float2bfloat16(tile[k32l * 32 + quad * 8 + j][col]);
        int k32 = kt * 2 + k32l;
        *(v8s*)(dst + (size_t)(h16 * 32 + k32) * 512 + l * 8) = *(v8s*)o;
    }
}

// ---------------------------------------------------------------------------
// Persistent LSTM. 512 blocks x 128 threads (2 waves), co-resident worst-case.
// Coherence protocol (NO acquire/release fences -> no buffer_inv/wbl2 storms):
//   - h stores: relaxed AGENT-scope atomic u64 stores -> sc0 sc1 write-through
//     to the coherence point. h buffers are write-once, so consumers' normal
//     cached loads can never see stale lines (first touch is post-flag).
//   - flags: relaxed atomic add / relaxed atomic spin loads (sc1, no inv).
//     Ordering: __syncthreads() drains vmcnt(0) per wave before s_barrier,
//     so all sc1 h-stores are globally visible before tid0 increments.
//   - weights stay L2-resident across all 64 steps (b%8==hblk%8 per-XCD slice).
// ---------------------------------------------------------------------------
__device__ inline void spinwait(const int* p, int target) {
    while (__hip_atomic_load(p, __ATOMIC_RELAXED, __HIP_MEMORY_SCOPE_AGENT) < target)
        __builtin_amdgcn_s_sleep(2);
}

__global__ __launch_bounds__(128, 1) void lstm_persist(
    const bf16* __restrict__ Xf,
    const bf16* __restrict__ Bf1, const bf16* __restrict__ Bf2,
    const float* __restrict__ bias1, const float* __restrict__ bias2,
    bf16* __restrict__ h1all, bf16* __restrict__ h2all,
    const bf16* __restrict__ hz,
    float* __restrict__ c1, float* __restrict__ c2,
    int* __restrict__ flags1, int* __restrict__ flags2)
{
    const int b = blockIdx.x;
    const int layer = b >> 8;
    const int idx = b & 255;
    const int hblk = idx & 63;
    const int mt = idx >> 6;

    const int nT = layer ? 64 : 48;
    const int nA = layer ? 32 : 16;
    const int half = nT >> 1;
    const bf16* __restrict__ Bf = layer ? Bf2 : Bf1;
    const float* __restrict__ bias = layer ? bias2 : bias1;
    float* __restrict__ cptr = layer ? c2 : c1;
    int* myflags = layer ? flags2 : flags1;
    bf16* hall = layer ? h2all : h1all;
    const size_t HB = (size_t)BATCH * HIDDEN;

    const int tid = threadIdx.x;
    const int kk = tid >> 6;
    const int lane = tid & 63;
    const int col = lane & 15, quad = lane >> 4;

    __shared__ float red[16 * 64 * 4];
    __shared__ float Zs[64][68];

    const bf16* Bb[4];
#pragma unroll
    for (int g = 0; g < 4; g++)
        Bb[g] = Bf + (size_t)((g * 64 + hblk) * nT) * 512 + lane * 8;

    const float bv[4] = {bias[0 * 1024 + hblk * 16 + col],
                         bias[1 * 1024 + hblk * 16 + col],
                         bias[2 * 1024 + hblk * 16 + col],
                         bias[3 * 1024 + hblk * 16 + col]};

    for (int t = 0; t < SEQ; t++) {
        if (tid == 0) {
            if (layer == 0) {
                if (t > 0) spinwait(flags1 + (t - 1) * 64, 256);
            } else {
                spinwait(flags1 + t * 64, 256);
                if (t > 0) spinwait(flags2 + (t - 1) * 64, 256);
            }
        }
        __syncthreads();

        const bf16 *A0base, *A1base;
        if (layer == 0) {
            A0base = Xf + (size_t)t * (BATCH * INPUT);
            A1base = t ? (h1all + (size_t)(t - 1) * HB) : hz;
        } else {
            A0base = h1all + (size_t)t * HB;
            A1base = t ? (h2all + (size_t)(t - 1) * HB) : hz;
        }
        const bf16 *ax[4], *ah[4];
#pragma unroll
        for (int i = 0; i < 4; i++) {
            int m16 = mt * 4 + i;
            ax[i] = A0base + (size_t)(m16 * nA) * 512 + lane * 8;
            ah[i] = A1base + (size_t)(m16 * 32) * 512 + lane * 8;
        }

        v4f acc[4][4] = {};
        v8s ra[4][4], rb[4][4];
        const int kbase = kk * half;

#define ISSUE(KCH, SLOT) do {                                                   \
    const int k_ = (KCH);                                                       \
    _Pragma("unroll")                                                           \
    for (int i_ = 0; i_ < 4; i_++) {                                            \
        const bf16* p_ = (k_ < nA) ? (ax[i_] + (size_t)k_ * 512)                \
                                   : (ah[i_] + (size_t)(k_ - nA) * 512);        \
        ra[SLOT][i_] = *(const v8s*)p_;                                         \
    }                                                                           \
    _Pragma("unroll")                                                           \
    for (int g_ = 0; g_ < 4; g_++)                                              \
        rb[SLOT][g_] = *(const v8s*)(Bb[g_] + (size_t)k_ * 512);                \
} while (0)

        ISSUE(kbase + 0, 0); ISSUE(kbase + 1, 1);
        ISSUE(kbase + 2, 2); ISSUE(kbase + 3, 3);

        for (int j0 = 0; j0 < half; j0 += 4) {
#pragma unroll
            for (int s = 0; s < 4; s++) {
#pragma unroll
                for (int mi = 0; mi < 4; mi++)
#pragma unroll
                    for (int g = 0; g < 4; g++)
                        acc[mi][g] = __builtin_amdgcn_mfma_f32_16x16x32_bf16(
                            ra[s][mi], rb[s][g], acc[mi][g], 0, 0, 0);
                const int nj = j0 + s + 4;
                if (nj < half) ISSUE(kbase + nj, s);
            }
        }
#undef ISSUE

        if (kk == 1) {
#pragma unroll
            for (int mi = 0; mi < 4; mi++)
#pragma unroll
                for (int g = 0; g < 4; g++)
                    *(v4f*)&red[(((mi * 4 + g) * 64) + lane) * 4] = acc[mi][g];
        }
        __syncthreads();
        if (kk == 0) {
#pragma unroll
            for (int mi = 0; mi < 4; mi++)
#pragma unroll
                for (int g = 0; g < 4; g++) {
                    v4f o = *(v4f*)&red[(((mi * 4 + g) * 64) + lane) * 4];
                    v4f z = acc[mi][g] + o;
#pragma unroll
                    for (int r = 0; r < 4; r++)
                        Zs[mi * 16 + quad * 4 + r][col * 4 + g] = z[r] + bv[g];
                }
        }
        __syncthreads();

        // fused LSTM cell: 64 m x 16 h, 8 cells/thread
        {
            const int m = tid >> 1, ch = tid & 1;
            const int mg = mt * 64 + m;
            const int hg = hblk * 16 + ch * 8;
            float* cp = cptr + (size_t)mg * HIDDEN + hg;
            float4 cv0 = *(float4*)cp;
            float4 cv1 = *(float4*)(cp + 4);
            float cold[8] = {cv0.x, cv0.y, cv0.z, cv0.w, cv1.x, cv1.y, cv1.z, cv1.w};
            float cnew[8];
            bf16 hv[8];
#pragma unroll
            for (int hh = 0; hh < 8; hh++) {
                const int zc = (ch * 8 + hh) * 4;
                float zi = Zs[m][zc], zf = Zs[m][zc + 1];
                float zg = Zs[m][zc + 2], zo = Zs[m][zc + 3];
                float ig = 1.f / (1.f + __expf(-zi));
                float fg = 1.f / (1.f + __expf(-zf));
                float e2g = __expf(2.f * zg);
                float gg = (e2g - 1.f) / (e2g + 1.f);
                float og = 1.f / (1.f + __expf(-zo));
                float cn = fg * cold[hh] + ig * gg;
                float e2c = __expf(2.f * cn);
                float th = (e2c - 1.f) / (e2c + 1.f);
                cnew[hh] = cn;
                hv[hh] = __float2bfloat16(og * th);
            }
            *(float4*)cp = make_float4(cnew[0], cnew[1], cnew[2], cnew[3]);
            *(float4*)(cp + 4) = make_float4(cnew[4], cnew[5], cnew[6], cnew[7]);
            bf16* hout = hall + (size_t)t * HB;
            const size_t hoff = (size_t)(((mg >> 4) * 32 + (hg >> 5)) * 64
                                         + ((hg >> 3) & 3) * 16 + (mg & 15)) * 8;
            // write-through (sc0 sc1) so the data reaches the coherence point
            unsigned long long* q = (unsigned long long*)hv;
            unsigned long long* dp = (unsigned long long*)(hout + hoff);
            __hip_atomic_store(dp,     q[0], __ATOMIC_RELAXED, __HIP_MEMORY_SCOPE_AGENT);
            __hip_atomic_store(dp + 1, q[1], __ATOMIC_RELAXED, __HIP_MEMORY_SCOPE_AGENT);
        }
        __syncthreads();   // per-wave vmcnt(0) drain before s_barrier -> h visible

        if (tid == 0) {
            __hip_atomic_fetch_add(myflags + t * 64, 1,
                                   __ATOMIC_RELAXED, __HIP_MEMORY_SCOPE_AGENT);
        }
    }
}

// ---------------- projection: out = h2(63) @ Wo + bo ----------------
__global__ __launch_bounds__(256, 2) void proj_kernel(
    const bf16* __restrict__ H,
    const bf16* __restrict__ Wof,
    const float* __restrict__ bo,
    float* __restrict__ Out)
{
    const int mblk = blockIdx.x, nblk = blockIdx.y;
    const int tid = threadIdx.x;
    const int lane = tid & 63;
    const int wave = tid >> 6;
    const int mw = wave >> 1, nw = wave & 1;
    const int col = lane & 15, quad = lane >> 4;

    const int m16 = mblk * 4 + mw * 2;
    const bf16* ah0 = H + (size_t)(m16 * 32) * 512 + lane * 8;
    const bf16* ah1 = H + (size_t)((m16 + 1) * 32) * 512 + lane * 8;
    const int n16a = nblk * 4 + nw * 2, n16b = n16a + 1;
    const bf16* bb0 = Wof + (size_t)(n16a * 32) * 512 + lane * 8;
    const bf16* bb1 = Wof + (size_t)(n16b * 32) * 512 + lane * 8;

    v4f acc00{}, acc01{}, acc10{}, acc11{};
    v8s ra0[8], ra1[8], rb0[8], rb1[8];

#define ISSUE(KK, SLOT) do {                          \
    const int kk_ = (KK);                             \
    ra0[SLOT] = *(const v8s*)(ah0 + kk_ * 512);       \
    ra1[SLOT] = *(const v8s*)(ah1 + kk_ * 512);       \
    rb0[SLOT] = *(const v8s*)(bb0 + kk_ * 512);       \
    rb1[SLOT] = *(const v8s*)(bb1 + kk_ * 512);       \
} while (0)

#pragma unroll
    for (int u = 0; u < 8; u++) ISSUE(u, u);

    for (int base = 0; base < 32; base += 8) {
#pragma unroll
        for (int u = 0; u < 8; u++) {
            acc00 = __builtin_amdgcn_mfma_f32_16x16x32_bf16(ra0[u], rb0[u], acc00, 0, 0, 0);
            acc01 = __builtin_amdgcn_mfma_f32_16x16x32_bf16(ra0[u], rb1[u], acc01, 0, 0, 0);
            acc10 = __builtin_amdgcn_mfma_f32_16x16x32_bf16(ra1[u], rb0[u], acc10, 0, 0, 0);
            acc11 = __builtin_amdgcn_mfma_f32_16x16x32_bf16(ra1[u], rb1[u], acc11, 0, 0, 0);
            const int k2 = base + u + 8;
            if (k2 < 32) ISSUE(k2, u);
        }
    }
#undef ISSUE

    const int n0 = n16a * 16 + col, n1 = n16b * 16 + col;
    const float bo0 = (n0 < CLASSES) ? bo[n0] : 0.f;
    const float bo1 = (n1 < CLASSES) ? bo[n1] : 0.f;
#pragma unroll
    for (int i = 0; i < 2; i++) {
        const int row = mblk * 64 + mw * 32 + i * 16 + quad * 4;
        v4f a0 = i ? acc10 : acc00;
        v4f a1 = i ? acc11 : acc01;
#pragma unroll
        for (int r = 0; r < 4; r++) {
            if (n0 < CLASSES) Out[(size_t)(row + r) * CLASSES + n0] = a0[r] + bo0;
            if (n1 < CLASSES) Out[(size_t)(row + r) * CLASSES + n1] = a1[r] + bo1;
        }
    }
}

// ---------------- launcher ----------------
extern "C" void kernel_launch(void* const* d_in, const int* in_sizes, int n_in,
                              void* d_out, int out_size, void* d_ws, size_t ws_size,
                              hipStream_t stream) {
    const float* x  = (const float*)d_in[0];
    const float* W1 = (const float*)d_in[1];
    const float* U1 = (const float*)d_in[2];
    const float* b1 = (const float*)d_in[3];
    const float* W2 = (const float*)d_in[4];
    const float* U2 = (const float*)d_in[5];
    const float* b2 = (const float*)d_in[6];
    const float* Wo = (const float*)d_in[7];
    const float* bo = (const float*)d_in[8];
    float* out = (float*)d_out;

    char* ws = (char*)d_ws;
    size_t off = 0;
    auto alloc = [&](size_t bytes) -> void* {
        void* p = ws + off;
        off += (bytes + 255) & ~(size_t)255;
        return p;
    };
    bf16* Xf    = (bf16*)alloc((size_t)SEQ * BATCH * INPUT * 2);
    bf16* Bf1   = (bf16*)alloc((size_t)256 * 48 * 512 * 2);
    bf16* Bf2   = (bf16*)alloc((size_t)256 * 64 * 512 * 2);
    bf16* Wof   = (bf16*)alloc((size_t)64 * 32 * 512 * 2);
    bf16* h1all = (bf16*)alloc((size_t)SEQ * BATCH * HIDDEN * 2);
    bf16* h2all = (bf16*)alloc((size_t)SEQ * BATCH * HIDDEN * 2);
    bf16* hz    = (bf16*)alloc((size_t)BATCH * HIDDEN * 2);
    float* c1   = (float*)alloc((size_t)BATCH * HIDDEN * 4);
    float* c2   = (float*)alloc((size_t)BATCH * HIDDEN * 4);
    int* flags1 = (int*)alloc(64 * 64 * 4);
    int* flags2 = (int*)alloc(64 * 64 * 4);

    hipMemsetAsync(hz, 0, (size_t)BATCH * HIDDEN * 2, stream);
    hipMemsetAsync(c1, 0, (size_t)BATCH * HIDDEN * 4, stream);
    hipMemsetAsync(c2, 0, (size_t)BATCH * HIDDEN * 4, stream);
    hipMemsetAsync(flags1, 0, 64 * 64 * 4, stream);
    hipMemsetAsync(flags2, 0, 64 * 64 * 4, stream);

    conv_x<<<4096, 256, 0, stream>>>(x, Xf);
    build_bf<<<dim3(24, 64, 4), 256, 0, stream>>>(W1, U1, 512, 48, Bf1);
    build_bf<<<dim3(32, 64, 4), 256, 0, stream>>>(W2, U2, 1024, 64, Bf2);
    build_wof<<<dim3(16, 64), 256, 0, stream>>>(Wo, Wof);

    lstm_persist<<<512, 128, 0, stream>>>(Xf, Bf1, Bf2, b1, b2,
                                          h1all, h2all, hz, c1, c2,
                                          flags1, flags2);

    proj_kernel<<<dim3(4, 16), 256, 0, stream>>>(
        h2all + (size_t)(SEQ - 1) * BATCH * HIDDEN, Wof, bo, out);
}

// Round 5
// 1137.107 us; speedup vs baseline: 4.0896x; 1.7842x over previous
//
#include <hip/hip_runtime.h>
#include <hip/hip_bf16.h>

typedef __hip_bfloat16 bf16;
typedef short v8s __attribute__((ext_vector_type(8)));
typedef float v4f __attribute__((ext_vector_type(4)));
typedef unsigned long long u64;

#define BATCH 256
#define SEQ 64
#define INPUT 512
#define HIDDEN 1024
#define CLASSES 1000

// ============================================================================
// Fragment-linear layouts (bf16):
//   A-chunk (16 m x 32 k): chunk[lane*8+j] = A[m16*16+(lane&15)][k32*32+(lane>>4)*8+j]
//   B-chunk (16 n x 32 k): chunk[lane*8+j] = W[k32*32+(lane>>4)*8+j][ncol]
// Xfrag:  [t][m16(16)][k32(16)][512]
// h-frag: [t][m16(16)][k32(32)][512]   (deep-buffered, write-once per address)
// Bf:     [hb(128)][n16l(2)][k32(NT)][512]; block hb covers h in [hb*8, hb*8+8):
//   n16l=0 cols = i-gate(8h), f-gate(8h); n16l=1 = g(8h), o(8h)
// Wof:    [n16(64)][k32(32)][512]
// ============================================================================

__global__ __launch_bounds__(256) void conv_x(const float* __restrict__ x,
                                              bf16* __restrict__ Xf) {
    int gid = blockIdx.x * 256 + threadIdx.x;
    int lane = gid & 63;
    int k32 = (gid >> 6) & 15;
    int m16 = (gid >> 10) & 15;
    int tt  = gid >> 14;
    int row = lane & 15, quad = lane >> 4;
    int b_ = m16 * 16 + row;
    int k  = k32 * 32 + quad * 8;
    const float* src = x + ((size_t)(b_ * SEQ + tt) * INPUT + k);
    float4 v0 = *(const float4*)src;
    float4 v1 = *(const float4*)(src + 4);
    bf16 o[8] = {__float2bfloat16(v0.x), __float2bfloat16(v0.y),
                 __float2bfloat16(v0.z), __float2bfloat16(v0.w),
                 __float2bfloat16(v1.x), __float2bfloat16(v1.y),
                 __float2bfloat16(v1.z), __float2bfloat16(v1.w)};
    bf16* dst = Xf + (size_t)(tt * 256 + m16 * 16 + k32) * 512 + lane * 8;
    *(v8s*)dst = *(v8s*)o;
}

// [W;U] fp32 -> Bf slices. grid (Ktot/64, 128, 2), block 256.
__global__ __launch_bounds__(256) void build_bf(const float* __restrict__ W,
                                                const float* __restrict__ U,
                                                int K0, int NT,
                                                bf16* __restrict__ dst) {
    __shared__ float tile[64][17];
    const int kt = blockIdx.x, hb = blockIdx.y, n16l = blockIdx.z;
    const int k0 = kt * 64;
    const int tid = threadIdx.x;
#pragma unroll
    for (int i = 0; i < 4; i++) {
        int idx = tid + i * 256;
        int c = idx & 15, kl = idx >> 4;
        int k = k0 + kl;
        int srccol = (n16l * 2 + (c >> 3)) * 1024 + hb * 8 + (c & 7);
        float v = (k < K0) ? W[(size_t)k * 4096 + srccol]
                           : U[(size_t)(k - K0) * 4096 + srccol];
        tile[kl][c] = v;
    }
    __syncthreads();
    if (tid < 128) {
        int k32l = tid >> 6, l = tid & 63;
        bf16 o[8];
#pragma unroll
        for (int j = 0; j < 8; j++)
            o[j] = __float2bfloat16(tile[k32l * 32 + (l >> 4) * 8 + j][l & 15]);
        *(v8s*)(dst + ((size_t)(hb * 2 + n16l) * NT + kt * 2 + k32l) * 512 + l * 8) = *(v8s*)o;
    }
}

__global__ __launch_bounds__(256) void build_wof(const float* __restrict__ Wo,
                                                 bf16* __restrict__ dst) {
    __shared__ float tile[64][17];
    const int h16 = blockIdx.y, kt = blockIdx.x;
    const int k0 = kt * 64, nb = h16 * 16;
    const int tid = threadIdx.x;
#pragma unroll
    for (int i = 0; i < 4; i++) {
        int idx = tid + i * 256;
        int kl = idx >> 4, c = idx & 15;
        int k = k0 + kl;
        float v = (nb + c < CLASSES) ? Wo[(size_t)k * CLASSES + nb + c] : 0.f;
        tile[kl][c] = v;
    }
    __syncthreads();
    if (tid < 128) {
        int k32l = tid >> 6, l = tid & 63;
        int col = l & 15, quad = l >> 4;
        bf16 o[8];
#pragma unroll
        for (int j = 0; j < 8; j++)
            o[j] = __float2bfloat16(tile[k32l * 32 + quad * 8 + j][col]);
        int k32 = kt * 2 + k32l;
        *(v8s*)(dst + (size_t)(h16 * 32 + k32) * 512 + l * 8) = *(v8s*)o;
    }
}

// ---------------------------------------------------------------------------
__device__ __forceinline__ void spinwait(const int* p, int target) {
    while (__hip_atomic_load(p, __ATOMIC_RELAXED, __HIP_MEMORY_SCOPE_AGENT) < target)
        __builtin_amdgcn_s_sleep(1);
}

// One layer's full 64-step recurrence. Block tile: 256 batch x 32 cols
// (8 h x 4 gates). Weights in LDS (Bl), c-state in registers, h exchanged
// through deep-buffered global with relaxed write-through + flag counters.
template<int NT, int NA>
__device__ __forceinline__ void run_layer(
    const bf16* __restrict__ A0all, size_t A0stride,
    bf16* __restrict__ hall,          // own-layer h deep buffer (also A1 source)
    const bf16* __restrict__ hz,
    const bf16* __restrict__ Bl,      // LDS: 2*NT chunks
    bf16* __restrict__ hstage,        // LDS: 4 KB
    const float* __restrict__ bias,   // raw b (gate-major)
    int hb,
    const int* __restrict__ waitA,    // producer flags for A0 (L2) or nullptr
    const int* __restrict__ waitSelf, // own-layer flags
    int* __restrict__ pub)
{
    const size_t HB = (size_t)BATCH * HIDDEN;
    const int tid = threadIdx.x;
    const int lane = tid & 63, wave = tid >> 6;
    const int col = lane & 15, quad = lane >> 4;
    const bool hicol = (col & 8) != 0;
    const int K32 = hb >> 2, Q = hb & 3;

    const float bI = bias[0 * 1024 + hb * 8 + (col & 7)];
    const float bF = bias[1 * 1024 + hb * 8 + (col & 7)];
    const float bG = bias[2 * 1024 + hb * 8 + (col & 7)];
    const float bO = bias[3 * 1024 + hb * 8 + (col & 7)];

    float cc[4] = {0.f, 0.f, 0.f, 0.f};   // cell state: registers, all 64 steps

    const bf16* bl0 = Bl + lane * 8;
    const bf16* bl1 = Bl + (size_t)NT * 512 + lane * 8;

    for (int t = 0; t < SEQ; t++) {
        if (tid == 0) {
            if (waitA) spinwait(waitA + t * 64, 128);
            if (t > 0) spinwait(waitSelf + (t - 1) * 64, 128);
        }
        __syncthreads();

        const bf16* A0 = A0all + (size_t)t * A0stride;
        const bf16* A1 = t ? (hall + (size_t)(t - 1) * HB) : hz;
        const bf16* ax0 = A0 + (size_t)((wave * 2 + 0) * NA) * 512 + lane * 8;
        const bf16* ax1 = A0 + (size_t)((wave * 2 + 1) * NA) * 512 + lane * 8;
        const bf16* ah0 = A1 + (size_t)((wave * 2 + 0) * 32) * 512 + lane * 8;
        const bf16* ah1 = A1 + (size_t)((wave * 2 + 1) * 32) * 512 + lane * 8;

        v4f acc[2][2] = {};
        v8s ra[8][2];
        v8s rb[4][2];

#define IA(K, S) do {                                                            \
    ra[S][0] = *(const v8s*)(((K) < NA) ? (ax0 + (size_t)(K) * 512)              \
                                        : (ah0 + (size_t)((K) - NA) * 512));     \
    ra[S][1] = *(const v8s*)(((K) < NA) ? (ax1 + (size_t)(K) * 512)              \
                                        : (ah1 + (size_t)((K) - NA) * 512));     \
} while (0)
#define IB(K, S) do {                                                            \
    rb[S][0] = *(const v8s*)(bl0 + (size_t)(K) * 512);                           \
    rb[S][1] = *(const v8s*)(bl1 + (size_t)(K) * 512);                           \
} while (0)

#pragma unroll
        for (int k = 0; k < 8; k++) IA(k, k);
#pragma unroll
        for (int k = 0; k < 4; k++) IB(k, k);

#pragma unroll
        for (int k = 0; k < NT; k++) {
            const int sa = k & 7, sb = k & 3;
            acc[0][0] = __builtin_amdgcn_mfma_f32_16x16x32_bf16(ra[sa][0], rb[sb][0], acc[0][0], 0, 0, 0);
            acc[0][1] = __builtin_amdgcn_mfma_f32_16x16x32_bf16(ra[sa][0], rb[sb][1], acc[0][1], 0, 0, 0);
            acc[1][0] = __builtin_amdgcn_mfma_f32_16x16x32_bf16(ra[sa][1], rb[sb][0], acc[1][0], 0, 0, 0);
            acc[1][1] = __builtin_amdgcn_mfma_f32_16x16x32_bf16(ra[sa][1], rb[sb][1], acc[1][1], 0, 0, 0);
            if (k + 8 < NT) IA(k + 8, sa);
            if (k + 4 < NT) IB(k + 4, sb);
        }
#undef IA
#undef IB

        // ---- epilogue: lane^8 gate exchange, register cell, LDS h-transpose ----
        // tile (mi, ni=0) cols: i(h=0..7), f(h=0..7); (mi, ni=1): g, o.
        // lane col<8 computes cells of m16a (mi=0); col>=8 of m16b. h = col&7.
#pragma unroll
        for (int r = 0; r < 4; r++) {
            float send0 = hicol ? acc[0][0][r] : acc[1][0][r];
            float send1 = hicol ? acc[0][1][r] : acc[1][1][r];
            float recv0 = __shfl_xor(send0, 8, 64);
            float recv1 = __shfl_xor(send1, 8, 64);
            float own0 = hicol ? acc[1][0][r] : acc[0][0][r];
            float own1 = hicol ? acc[1][1][r] : acc[0][1][r];
            float zi = (hicol ? recv0 : own0) + bI;
            float zf = (hicol ? own0 : recv0) + bF;
            float zg = (hicol ? recv1 : own1) + bG;
            float zo = (hicol ? own1 : recv1) + bO;
            float ig = 1.f / (1.f + __expf(-zi));
            float fg = 1.f / (1.f + __expf(-zf));
            float e2g = __expf(2.f * zg);
            float gg = (e2g - 1.f) / (e2g + 1.f);
            float og = 1.f / (1.f + __expf(-zo));
            float cn = fg * cc[r] + ig * gg;
            float e2c = __expf(2.f * cn);
            float th = (e2c - 1.f) / (e2c + 1.f);
            cc[r] = cn;
            int m_local = wave * 32 + (hicol ? 16 : 0) + quad * 4 + r;
            hstage[m_local * 8 + (col & 7)] = __float2bfloat16(og * th);
        }

        // flush: lanes 0..31 each emit one m-row (8 h = 16 B) write-through
        if (lane < 32) {
            int row = wave * 32 + lane;
            v8s hv = *(const v8s*)(hstage + row * 8);
            bf16* houtt = hall + (size_t)t * HB;
            size_t eoff = ((size_t)(row >> 4) * 32 + K32) * 512
                        + (size_t)((row & 15) + 16 * Q) * 8;
            u64 qq[2];
            *(v8s*)qq = hv;
            u64* dp = (u64*)(houtt + eoff);
            __hip_atomic_store(dp,     qq[0], __ATOMIC_RELAXED, __HIP_MEMORY_SCOPE_AGENT);
            __hip_atomic_store(dp + 1, qq[1], __ATOMIC_RELAXED, __HIP_MEMORY_SCOPE_AGENT);
        }
        __syncthreads();   // all waves drain vmcnt before publish

        if (tid == 0)
            __hip_atomic_fetch_add(pub + t * 64, 1,
                                   __ATOMIC_RELAXED, __HIP_MEMORY_SCOPE_AGENT);
    }
}

__global__ __launch_bounds__(512, 2) void lstm_persist(
    const bf16* __restrict__ Xf,
    const bf16* __restrict__ Bf1, const bf16* __restrict__ Bf2,
    const float* __restrict__ b1, const float* __restrict__ b2,
    bf16* __restrict__ h1all, bf16* __restrict__ h2all,
    const bf16* __restrict__ hz,
    int* __restrict__ flags1, int* __restrict__ flags2)
{
    extern __shared__ char smem[];
    bf16* Bl = (bf16*)smem;
    bf16* hstage = (bf16*)(smem + 131072);

    const int b = blockIdx.x;
    const int layer = b >> 7;
    const int hb = b & 127;
    const int tid = threadIdx.x;

    // one-time weight slice -> LDS (96 KB L1 / 128 KB L2)
    {
        const int NTl = layer ? 64 : 48;
        const bf16* Bsrc = (layer ? Bf2 : Bf1) + (size_t)(hb * 2 * NTl) * 512;
        const int nbytes = NTl * 2 * 1024;
        for (int o = tid * 16; o < nbytes; o += 512 * 16)
            *(uint4*)(smem + o) = *(const uint4*)((const char*)Bsrc + o);
    }
    __syncthreads();

    if (layer == 0)
        run_layer<48, 16>(Xf, (size_t)BATCH * INPUT, h1all, hz, Bl, hstage,
                          b1, hb, nullptr, flags1, flags1);
    else
        run_layer<64, 32>(h1all, (size_t)BATCH * HIDDEN, h2all, hz, Bl, hstage,
                          b2, hb, flags1, flags2, flags2);
}

// ---------------- projection: out = h2(63) @ Wo + bo ----------------
__global__ __launch_bounds__(256, 2) void proj_kernel(
    const bf16* __restrict__ H,
    const bf16* __restrict__ Wof,
    const float* __restrict__ bo,
    float* __restrict__ Out)
{
    const int mblk = blockIdx.x, nblk = blockIdx.y;
    const int tid = threadIdx.x;
    const int lane = tid & 63;
    const int wave = tid >> 6;
    const int mw = wave >> 1, nw = wave & 1;
    const int col = lane & 15, quad = lane >> 4;

    const int m16 = mblk * 4 + mw * 2;
    const bf16* ah0 = H + (size_t)(m16 * 32) * 512 + lane * 8;
    const bf16* ah1 = H + (size_t)((m16 + 1) * 32) * 512 + lane * 8;
    const int n16a = nblk * 4 + nw * 2, n16b = n16a + 1;
    const bf16* bb0 = Wof + (size_t)(n16a * 32) * 512 + lane * 8;
    const bf16* bb1 = Wof + (size_t)(n16b * 32) * 512 + lane * 8;

    v4f acc00{}, acc01{}, acc10{}, acc11{};
    v8s ra0[8], ra1[8], rb0[8], rb1[8];

#define ISSUE(KK, SLOT) do {                          \
    const int kk_ = (KK);                             \
    ra0[SLOT] = *(const v8s*)(ah0 + kk_ * 512);       \
    ra1[SLOT] = *(const v8s*)(ah1 + kk_ * 512);       \
    rb0[SLOT] = *(const v8s*)(bb0 + kk_ * 512);       \
    rb1[SLOT] = *(const v8s*)(bb1 + kk_ * 512);       \
} while (0)

#pragma unroll
    for (int u = 0; u < 8; u++) ISSUE(u, u);

    for (int base = 0; base < 32; base += 8) {
#pragma unroll
        for (int u = 0; u < 8; u++) {
            acc00 = __builtin_amdgcn_mfma_f32_16x16x32_bf16(ra0[u], rb0[u], acc00, 0, 0, 0);
            acc01 = __builtin_amdgcn_mfma_f32_16x16x32_bf16(ra0[u], rb1[u], acc01, 0, 0, 0);
            acc10 = __builtin_amdgcn_mfma_f32_16x16x32_bf16(ra1[u], rb0[u], acc10, 0, 0, 0);
            acc11 = __builtin_amdgcn_mfma_f32_16x16x32_bf16(ra1[u], rb1[u], acc11, 0, 0, 0);
            const int k2 = base + u + 8;
            if (k2 < 32) ISSUE(k2, u);
        }
    }
#undef ISSUE

    const int n0 = n16a * 16 + col, n1 = n16b * 16 + col;
    const float bo0 = (n0 < CLASSES) ? bo[n0] : 0.f;
    const float bo1 = (n1 < CLASSES) ? bo[n1] : 0.f;
#pragma unroll
    for (int i = 0; i < 2; i++) {
        const int row = mblk * 64 + mw * 32 + i * 16 + quad * 4;
        v4f a0 = i ? acc10 : acc00;
        v4f a1 = i ? acc11 : acc01;
#pragma unroll
        for (int r = 0; r < 4; r++) {
            if (n0 < CLASSES) Out[(size_t)(row + r) * CLASSES + n0] = a0[r] + bo0;
            if (n1 < CLASSES) Out[(size_t)(row + r) * CLASSES + n1] = a1[r] + bo1;
        }
    }
}

// ---------------- launcher ----------------
extern "C" void kernel_launch(void* const* d_in, const int* in_sizes, int n_in,
                              void* d_out, int out_size, void* d_ws, size_t ws_size,
                              hipStream_t stream) {
    const float* x  = (const float*)d_in[0];
    const float* W1 = (const float*)d_in[1];
    const float* U1 = (const float*)d_in[2];
    const float* b1 = (const float*)d_in[3];
    const float* W2 = (const float*)d_in[4];
    const float* U2 = (const float*)d_in[5];
    const float* b2 = (const float*)d_in[6];
    const float* Wo = (const float*)d_in[7];
    const float* bo = (const float*)d_in[8];
    float* out = (float*)d_out;

    char* ws = (char*)d_ws;
    size_t off = 0;
    auto alloc = [&](size_t bytes) -> void* {
        void* p = ws + off;
        off += (bytes + 255) & ~(size_t)255;
        return p;
    };
    bf16* Xf    = (bf16*)alloc((size_t)SEQ * BATCH * INPUT * 2);   // 16.8 MB
    bf16* Bf1   = (bf16*)alloc((size_t)128 * 2 * 48 * 512 * 2);    // 12.6 MB
    bf16* Bf2   = (bf16*)alloc((size_t)128 * 2 * 64 * 512 * 2);    // 16.8 MB
    bf16* Wof   = (bf16*)alloc((size_t)64 * 32 * 512 * 2);         // 2 MB
    bf16* h1all = (bf16*)alloc((size_t)SEQ * BATCH * HIDDEN * 2);  // 33.6 MB
    bf16* h2all = (bf16*)alloc((size_t)SEQ * BATCH * HIDDEN * 2);  // 33.6 MB
    bf16* hz    = (bf16*)alloc((size_t)BATCH * HIDDEN * 2);
    int* flags1 = (int*)alloc(64 * 64 * 4);
    int* flags2 = (int*)alloc(64 * 64 * 4);

    hipMemsetAsync(hz, 0, (size_t)BATCH * HIDDEN * 2, stream);
    hipMemsetAsync(flags1, 0, 64 * 64 * 4, stream);
    hipMemsetAsync(flags2, 0, 64 * 64 * 4, stream);

    conv_x<<<4096, 256, 0, stream>>>(x, Xf);
    build_bf<<<dim3(24, 128, 2), 256, 0, stream>>>(W1, U1, 512, 48, Bf1);
    build_bf<<<dim3(32, 128, 2), 256, 0, stream>>>(W2, U2, 1024, 64, Bf2);
    build_wof<<<dim3(16, 64), 256, 0, stream>>>(Wo, Wof);

    lstm_persist<<<256, 512, 135168, stream>>>(Xf, Bf1, Bf2, b1, b2,
                                               h1all, h2all, hz, flags1, flags2);

    proj_kernel<<<dim3(4, 16), 256, 0, stream>>>(
        h2all + (size_t)(SEQ - 1) * BATCH * HIDDEN, Wof, bo, out);
}